// Round 7
// baseline (471.779 us; speedup 1.0000x reference)
//
#include <hip/hip_runtime.h>
#include <hip/hip_bf16.h>

#define Bdim 4
#define Sdim 1024
#define Ddim 1024
#define Hdim 16
#define HDdim 64

typedef __attribute__((ext_vector_type(8))) short short8;   // 8 bf16 = A/B frag
typedef __attribute__((ext_vector_type(4))) float f32x4;    // C/D frag
typedef __attribute__((ext_vector_type(2))) unsigned int uint2v;
typedef __attribute__((ext_vector_type(4))) unsigned short ushort4v;

#define AS1 __attribute__((address_space(1)))
#define AS3 __attribute__((address_space(3)))

__device__ __forceinline__ unsigned short f2bf(float x) {
    unsigned int u = __builtin_bit_cast(unsigned int, x);
    return (unsigned short)((u + 0x7fffu + ((u >> 16) & 1u)) >> 16);  // RNE
}
__device__ __forceinline__ float bf2f(unsigned short u) {
    unsigned int v = ((unsigned int)u) << 16;
    return __builtin_bit_cast(float, v);
}

// ---------------- fp32 -> bf16 elementwise (x) ----------------
__global__ __launch_bounds__(256) void conv_bf16(const float* __restrict__ in,
                                                 unsigned short* __restrict__ out) {
    int i = blockIdx.x * 256 + threadIdx.x;
    float4 v = ((const float4*)in)[i];
    uint2v p;
    p.x = (unsigned)f2bf(v.x) | ((unsigned)f2bf(v.y) << 16);
    p.y = (unsigned)f2bf(v.z) | ((unsigned)f2bf(v.w) << 16);
    ((uint2v*)out)[i] = p;
}

// ---------------- fp32 [K][N] -> bf16 transposed [N][K] ----------------
__global__ __launch_bounds__(256) void transpose_bf16(const float* __restrict__ W,
                                                      unsigned short* __restrict__ Wt,
                                                      int K, int N) {
    __shared__ float t[32][33];
    const int tk = blockIdx.y * 32, tn = blockIdx.x * 32;
    const int r = threadIdx.x >> 5, c = threadIdx.x & 31;
    #pragma unroll
    for (int j = 0; j < 4; j++)
        t[r + 8 * j][c] = W[(size_t)(tk + r + 8 * j) * N + tn + c];
    __syncthreads();
    #pragma unroll
    for (int j = 0; j < 4; j++) {
        int nn = r + 8 * j;
        Wt[(size_t)(tn + nn) * K + tk + c] = f2bf(t[c][nn]);
    }
}

// ---------------- override prep: ovr fp32 -> bf16; mask int32 -> bit-packed u64 ----------------
__global__ __launch_bounds__(256) void ovr_prep(const float* __restrict__ ovr,
                                                const int* __restrict__ msk,
                                                unsigned short* __restrict__ ovrb,
                                                unsigned long long* __restrict__ mbits) {
    size_t i = (size_t)blockIdx.x * 256 + threadIdx.x;
    ovrb[i] = f2bf(ovr[i]);
    unsigned long long bal = __ballot(msk[i] != 0);
    if ((threadIdx.x & 63) == 0) mbits[i >> 6] = bal;
}

// ---------------- K/V prep: K fp32->bf16 same layout; V fp32 -> bf16 transposed [bh][d][s] ----
__global__ __launch_bounds__(256) void kv_prep(const float* __restrict__ kout,
                                               const float* __restrict__ vout,
                                               unsigned short* __restrict__ Kb,
                                               unsigned short* __restrict__ Vtr) {
    const int bh = blockIdx.y;
    const int s0 = blockIdx.x * 64;
    const int tid = threadIdx.x;
    __shared__ float t[64][65];
    const float4* kbase = (const float4*)(kout + ((size_t)bh * Sdim + s0) * HDdim);
    const float4* vbase = (const float4*)(vout + ((size_t)bh * Sdim + s0) * HDdim);
    uint2v* kb = (uint2v*)(Kb + ((size_t)bh * Sdim + s0) * HDdim);
    #pragma unroll
    for (int i = 0; i < 4; i++) {
        int idx = tid + i * 256;           // 1024 float4s = 64 rows x 16
        float4 v = kbase[idx];
        uint2v p;
        p.x = (unsigned)f2bf(v.x) | ((unsigned)f2bf(v.y) << 16);
        p.y = (unsigned)f2bf(v.z) | ((unsigned)f2bf(v.w) << 16);
        kb[idx] = p;
        float4 vv = vbase[idx];
        int r = idx >> 4, c = (idx & 15) * 4;
        t[r][c + 0] = vv.x; t[r][c + 1] = vv.y; t[r][c + 2] = vv.z; t[r][c + 3] = vv.w;
    }
    __syncthreads();
    #pragma unroll
    for (int i = 0; i < 4; i++) {
        int idx = tid + i * 256;
        int d = idx >> 4, sc = (idx & 15) * 4;
        uint2v p;
        p.x = (unsigned)f2bf(t[sc + 0][d]) | ((unsigned)f2bf(t[sc + 1][d]) << 16);
        p.y = (unsigned)f2bf(t[sc + 2][d]) | ((unsigned)f2bf(t[sc + 3][d]) << 16);
        *(uint2v*)(Vtr + (size_t)bh * HDdim * Sdim + (size_t)d * Sdim + s0 + sc) = p;
    }
}

// ---------------- bf16 MFMA GEMM body (m97 structure) ----------------
#define GEMM_BODY(Aptr, Bptr)                                                          \
    __shared__ unsigned short As[128 * 32];                                            \
    __shared__ unsigned short Bs[128 * 32];                                            \
    const int tid = threadIdx.x;                                                       \
    const int lane = tid & 63, w = tid >> 6;                                           \
    const int wm = w >> 1, wn = w & 1;                                                 \
    const int l15 = lane & 15, lg = lane >> 4;                                         \
    const int tile_m = blockIdx.y * 128, tile_n = blockIdx.x * 128;                    \
    f32x4 acc[4][4] = {};                                                              \
    for (int k0 = 0; k0 < 1024; k0 += 32) {                                            \
        _Pragma("unroll")                                                              \
        for (int j = 0; j < 2; j++) {                                                  \
            int ca = j * 256 + tid;                                                    \
            int rowa = ca >> 2, offa = (ca & 3) * 16;                                  \
            const char* ga = (const char*)(Aptr) +                                     \
                ((size_t)(tile_m + rowa) * 1024 + k0) * 2 + offa;                      \
            char* la = (char*)As + (j * 256 + w * 64) * 16;                            \
            __builtin_amdgcn_global_load_lds((const AS1 void*)ga, (AS3 void*)la,       \
                                             16, 0, 0);                                \
            const char* gb = (const char*)(Bptr) +                                     \
                ((size_t)(tile_n + rowa) * 1024 + k0) * 2 + offa;                      \
            char* lb = (char*)Bs + (j * 256 + w * 64) * 16;                            \
            __builtin_amdgcn_global_load_lds((const AS1 void*)gb, (AS3 void*)lb,       \
                                             16, 0, 0);                                \
        }                                                                              \
        __syncthreads();                                                               \
        short8 af[4], bfr[4];                                                          \
        _Pragma("unroll")                                                              \
        for (int t4 = 0; t4 < 4; t4++) {                                               \
            af[t4] = *(const short8*)((const char*)As +                                \
                        (wm * 64 + t4 * 16 + l15) * 64 + lg * 16);                     \
            bfr[t4] = *(const short8*)((const char*)Bs +                               \
                        (wn * 64 + t4 * 16 + l15) * 64 + lg * 16);                     \
        }                                                                              \
        _Pragma("unroll")                                                              \
        for (int i = 0; i < 4; i++)                                                    \
            _Pragma("unroll")                                                          \
            for (int j2 = 0; j2 < 4; j2++)                                             \
                acc[i][j2] = __builtin_amdgcn_mfma_f32_16x16x32_bf16(                  \
                    af[i], bfr[j2], acc[i][j2], 0, 0, 0);                              \
        __syncthreads();                                                               \
    }

// QKV: N=3072, routes q (bf16, pre-scaled 1/8) / k / v
__global__ __launch_bounds__(256) void gemm_qkv_mfma(const unsigned short* __restrict__ Xb,
                                                     const unsigned short* __restrict__ Wt,
                                                     const float* __restrict__ bias,
                                                     unsigned short* __restrict__ qbuf,
                                                     float* __restrict__ kout,
                                                     float* __restrict__ vout) {
    GEMM_BODY(Xb, Wt)
    const int seg = tile_n >> 10;
    #pragma unroll
    for (int i = 0; i < 4; i++) {
        #pragma unroll
        for (int j2 = 0; j2 < 4; j2++) {
            int n = tile_n + wn * 64 + j2 * 16 + l15;
            float bv = bias[n];
            int nn = n & 1023, h = nn >> 6, d = nn & 63;
            #pragma unroll
            for (int r = 0; r < 4; r++) {
                int m = tile_m + wm * 64 + i * 16 + 4 * lg + r;
                float v = acc[i][j2][r] + bv;
                int bb = m >> 10, s = m & 1023;
                size_t oidx = ((size_t)((bb * Hdim + h) * Sdim + s)) * HDdim + d;
                if (seg == 0) qbuf[oidx] = f2bf(v * 0.125f);
                else if (seg == 1) kout[oidx] = v;
                else vout[oidx] = v;
            }
        }
    }
}

// Proj: N=1024, plain fp32 out + bias
__global__ __launch_bounds__(256) void gemm_proj_mfma(const unsigned short* __restrict__ Ab,
                                                      const unsigned short* __restrict__ Wt,
                                                      const float* __restrict__ bias,
                                                      float* __restrict__ out) {
    GEMM_BODY(Ab, Wt)
    #pragma unroll
    for (int i = 0; i < 4; i++) {
        #pragma unroll
        for (int j2 = 0; j2 < 4; j2++) {
            int n = tile_n + wn * 64 + j2 * 16 + l15;
            float bv = bias[n];
            #pragma unroll
            for (int r = 0; r < 4; r++) {
                int m = tile_m + wm * 64 + i * 16 + 4 * lg + r;
                out[(size_t)m * Ddim + n] = acc[i][j2][r] + bv;
            }
        }
    }
}

// ---------------- MFMA attention v2: all-bf16 inputs, direct-global frags, no barriers ---
__global__ __launch_bounds__(256) void attn_mfma2(const unsigned short* __restrict__ qbuf,
                                                  const unsigned short* __restrict__ Kb,
                                                  const unsigned short* __restrict__ Vtr,
                                                  const unsigned short* __restrict__ ovrb,
                                                  const unsigned long long* __restrict__ mbits,
                                                  unsigned short* __restrict__ abuf) {
    const int qt = blockIdx.x;          // 0..15
    const int bh = blockIdx.y;          // 0..63
    const int h = bh & (Hdim - 1);
    const int b = bh >> 4;
    const int tid = threadIdx.x;
    const int wq = tid >> 6;
    const int lane = tid & 63;
    const int l15 = lane & 15;
    const int lg = lane >> 4;           // 0..3

    __shared__ unsigned short Ps[4][16 * 64];  // per-wave P [q][k] bf16, swizzled (8KB)

    const unsigned short* kb = Kb + (size_t)bh * Sdim * HDdim;    // [s][64]
    const unsigned short* vt = Vtr + (size_t)bh * HDdim * Sdim;   // [d][1024]
    const int qrow = qt * 64 + wq * 16 + l15;

    // Q B-frags (prescaled bf16): elem i of frag f <-> d = 8*lg+32*f+i
    short8 qf[2];
    {
        const unsigned short* qr = qbuf + ((size_t)bh * Sdim + qrow) * HDdim;
        qf[0] = *(const short8*)(qr + 8 * lg);
        qf[1] = *(const short8*)(qr + 8 * lg + 32);
    }

    // ---- Sweep 1: causal online (m,l), registers only, no LDS ----
    float m_run = -1e30f, l_run = 0.f;
    for (int kt = 0; kt <= qt; kt++) {
        float sv[16];
        const bool diag = (kt == qt);
        #pragma unroll
        for (int ks = 0; ks < 4; ks++) {
            const unsigned short* krow = kb + (size_t)(kt * 64 + ks * 16 + l15) * HDdim;
            short8 a0 = *(const short8*)(krow + 8 * lg);
            short8 a1 = *(const short8*)(krow + 8 * lg + 32);
            f32x4 c = {0.f, 0.f, 0.f, 0.f};
            c = __builtin_amdgcn_mfma_f32_16x16x32_bf16(a0, qf[0], c, 0, 0, 0);
            c = __builtin_amdgcn_mfma_f32_16x16x32_bf16(a1, qf[1], c, 0, 0, 0);
            #pragma unroll
            for (int r = 0; r < 4; r++) {
                int kg = kt * 64 + ks * 16 + 4 * lg + r;
                float s = c[r];
                if (diag && kg > qrow) s = -1e30f;
                sv[ks * 4 + r] = s;
            }
        }
        float tm = -1e30f;
        #pragma unroll
        for (int i = 0; i < 16; i++) tm = fmaxf(tm, sv[i]);
        tm = fmaxf(tm, __shfl_xor(tm, 16));
        tm = fmaxf(tm, __shfl_xor(tm, 32));
        float mn = fmaxf(m_run, tm);
        float ts = 0.f;
        #pragma unroll
        for (int i = 0; i < 16; i++) ts += __expf(sv[i] - mn);
        ts += __shfl_xor(ts, 16);
        ts += __shfl_xor(ts, 32);
        l_run = l_run * __expf(m_run - mn) + ts;
        m_run = mn;
    }
    const float inv_l = 1.f / l_run;

    // ---- Sweep 2: all 16 k-tiles ----
    f32x4 acc[4];
    #pragma unroll
    for (int ds = 0; ds < 4; ds++) acc[ds] = (f32x4){0.f, 0.f, 0.f, 0.f};
    const unsigned short* ob_base = ovrb + ((size_t)h * Sdim + qrow) * Sdim;
    const unsigned long long* mb_base = mbits + ((size_t)h * Sdim + qrow) * (Sdim / 64);

    for (int kt = 0; kt < 16; kt++) {
        float w[16];
        if (kt <= qt) {
            const bool diag = (kt == qt);
            #pragma unroll
            for (int ks = 0; ks < 4; ks++) {
                const unsigned short* krow = kb + (size_t)(kt * 64 + ks * 16 + l15) * HDdim;
                short8 a0 = *(const short8*)(krow + 8 * lg);
                short8 a1 = *(const short8*)(krow + 8 * lg + 32);
                f32x4 c = {0.f, 0.f, 0.f, 0.f};
                c = __builtin_amdgcn_mfma_f32_16x16x32_bf16(a0, qf[0], c, 0, 0, 0);
                c = __builtin_amdgcn_mfma_f32_16x16x32_bf16(a1, qf[1], c, 0, 0, 0);
                #pragma unroll
                for (int r = 0; r < 4; r++) {
                    int kg = kt * 64 + ks * 16 + 4 * lg + r;
                    float p = __expf(c[r] - m_run) * inv_l;
                    if (diag && kg > qrow) p = 0.f;
                    w[ks * 4 + r] = p;
                }
            }
        } else {
            #pragma unroll
            for (int i = 0; i < 16; i++) w[i] = 0.f;
        }
        // override: one u64 mask word covers this kt's 64 keys
        unsigned long long mw = mb_base[kt];
        #pragma unroll
        for (int ks = 0; ks < 4; ks++) {
            int kb0 = kt * 64 + ks * 16 + 4 * lg;
            ushort4v o4 = *(const ushort4v*)(ob_base + kb0);
            int bit0 = ks * 16 + 4 * lg;
            #pragma unroll
            for (int r = 0; r < 4; r++)
                if ((mw >> (bit0 + r)) & 1ULL) w[ks * 4 + r] = bf2f(o4[r]);
        }
        // store P packed 8B (4 consecutive bf16), XOR-swizzled
        #pragma unroll
        for (int ks = 0; ks < 4; ks++) {
            uint2v p;
            p.x = (unsigned)f2bf(w[ks * 4 + 0]) | ((unsigned)f2bf(w[ks * 4 + 1]) << 16);
            p.y = (unsigned)f2bf(w[ks * 4 + 2]) | ((unsigned)f2bf(w[ks * 4 + 3]) << 16);
            int byte = l15 * 128 + (ks * 16 + 4 * lg) * 2;
            byte ^= (l15 & 7) << 4;
            *(uint2v*)((char*)(Ps[wq]) + byte) = p;
        }
        // PV: A-frag from Ps (wave-local), B-frags direct from global Vtr
        int pbyte0 = l15 * 128 + lg * 16;
        pbyte0 ^= (l15 & 7) << 4;
        short8 pa0 = *(const short8*)((const char*)(Ps[wq]) + pbyte0);
        short8 pa1 = *(const short8*)((const char*)(Ps[wq]) + (pbyte0 ^ 64));
        #pragma unroll
        for (int ds = 0; ds < 4; ds++) {
            const unsigned short* vrow = vt + (size_t)(ds * 16 + l15) * Sdim + kt * 64;
            short8 v0 = *(const short8*)(vrow + 8 * lg);
            short8 v1 = *(const short8*)(vrow + 8 * lg + 32);
            acc[ds] = __builtin_amdgcn_mfma_f32_16x16x32_bf16(pa0, v0, acc[ds], 0, 0, 0);
            acc[ds] = __builtin_amdgcn_mfma_f32_16x16x32_bf16(pa1, v1, acc[ds], 0, 0, 0);
        }
    }

    // epilogue: C row=4*lg+r (q), col=l15 (d); bf16 out for proj A-operand
    #pragma unroll
    for (int ds = 0; ds < 4; ds++) {
        #pragma unroll
        for (int r = 0; r < 4; r++) {
            int q = qt * 64 + wq * 16 + 4 * lg + r;
            int d = h * HDdim + ds * 16 + l15;
            abuf[((size_t)(b * Sdim + q)) * Ddim + d] = f2bf(acc[ds][r]);
        }
    }
}

extern "C" void kernel_launch(void* const* d_in, const int* in_sizes, int n_in,
                              void* d_out, int out_size, void* d_ws, size_t ws_size,
                              hipStream_t stream) {
    const float* x       = (const float*)d_in[0];
    const float* w_attn  = (const float*)d_in[1];
    const float* b_attn  = (const float*)d_in[2];
    const float* w_proj  = (const float*)d_in[3];
    const float* b_proj  = (const float*)d_in[4];
    const float* ovr     = (const float*)d_in[5];
    const int*   msk     = (const int*)d_in[6];

    float* out = (float*)d_out;
    float* a_out = out;                                       // [B,S,D]
    float* kout  = out + (size_t)Bdim * Sdim * Ddim;          // present[0] [B,H,S,HD]
    float* vout  = kout + (size_t)Bdim * Hdim * Sdim * HDdim; // present[1]

    char* ws = (char*)d_ws;
    unsigned short* qbuf = (unsigned short*)ws;                 // 8 MB  q bf16 *0.125 [B,H,S,64]
    unsigned short* abuf = (unsigned short*)(ws + (8  << 20));  // 8 MB  attn out bf16 [B,S,D]
    unsigned short* Xb   = (unsigned short*)(ws + (16 << 20));  // 8 MB  x bf16
    unsigned short* Wta  = (unsigned short*)(ws + (24 << 20));  // 6 MB  w_attn^T bf16 [3072][1024]
    unsigned short* Wtp  = (unsigned short*)(ws + (30 << 20));  // 2 MB  w_proj^T bf16 [1024][1024]
    unsigned short* Kb   = (unsigned short*)(ws + (32 << 20));  // 8 MB  K bf16 [B,H,S,64]
    unsigned short* Vtr  = (unsigned short*)(ws + (40 << 20));  // 8 MB  V^T bf16 [B,H,64,S]
    unsigned short* ovrb = (unsigned short*)(ws + (48 << 20));  // 32 MB ovr bf16 [H,S,S]
    unsigned long long* mbits = (unsigned long long*)(ws + (80 << 20)); // 2 MB mask bits

    // prep (independent of GEMM): bf16 conversions, transposes, override packing
    conv_bf16<<<dim3(4096), 256, 0, stream>>>(x, Xb);
    transpose_bf16<<<dim3(96, 32), 256, 0, stream>>>(w_attn, Wta, 1024, 3072);
    transpose_bf16<<<dim3(32, 32), 256, 0, stream>>>(w_proj, Wtp, 1024, 1024);
    ovr_prep<<<dim3(65536), 256, 0, stream>>>(ovr, msk, ovrb, mbits);

    // 1) QKV GEMM (MFMA)
    gemm_qkv_mfma<<<dim3(24, 32), 256, 0, stream>>>(Xb, Wta, b_attn, qbuf, kout, vout);

    // K/V bf16 copies for attention
    kv_prep<<<dim3(16, 64), 256, 0, stream>>>(kout, vout, Kb, Vtr);

    // 2) attention
    attn_mfma2<<<dim3(16, 64), 256, 0, stream>>>(qbuf, Kb, Vtr, ovrb, mbits, abuf);

    // 3) output projection (MFMA)
    gemm_proj_mfma<<<dim3(8, 32), 256, 0, stream>>>(abuf, Wtp, b_proj, a_out);
}